// Round 17
// baseline (184.048 us; speedup 1.0000x reference)
//
#include <hip/hip_runtime.h>
#include <math.h>
#include <stdint.h>

#define BB 4
#define SS 2048
#define DDIM 1024
#define HH 16
#define HD 64
#define QKVLD 3072
#define QSCALE (0.125f * 1.44269504089f)

typedef __bf16 bf16x8 __attribute__((ext_vector_type(8)));
typedef float f32x4 __attribute__((ext_vector_type(4)));
typedef float f32x16 __attribute__((ext_vector_type(16)));
typedef int i32x4 __attribute__((ext_vector_type(4)));

// ---------------- helpers ----------------
__device__ __forceinline__ unsigned short f2bf(float f) {
    union { float f; unsigned u; } v; v.f = f;
    unsigned r = (v.u + 0x7FFFu + ((v.u >> 16) & 1u)) >> 16;
    return (unsigned short)r;
}
__device__ __forceinline__ void gload_lds16(const unsigned short* g, unsigned char* s) {
    __builtin_amdgcn_global_load_lds(
        (const __attribute__((address_space(1))) unsigned int*)(g),
        (__attribute__((address_space(3))) unsigned int*)(s), 16, 0, 0);
}

// ---------------------------------------------------------------------------
// Merged prep: x -> bf16 (8192 blks), W4 -> bf16 (4096 blks), rope table (256)
// ---------------------------------------------------------------------------
__global__ void prep_all(const float* __restrict__ x,
                         const float* __restrict__ Wq, const float* __restrict__ Wk,
                         const float* __restrict__ Wv, const float* __restrict__ Wo,
                         unsigned short* __restrict__ xb,
                         unsigned short* __restrict__ wqkv, unsigned short* __restrict__ wob,
                         float* __restrict__ cosT, float* __restrict__ sinT) {
    int bid = blockIdx.x;
    if (bid < 8192) {
        int i = bid * 256 + threadIdx.x;
        float4 v = ((const float4*)x)[i];
        ushort4 o;
        o.x = f2bf(v.x); o.y = f2bf(v.y); o.z = f2bf(v.z); o.w = f2bf(v.w);
        ((ushort4*)xb)[i] = o;
    } else if (bid < 12288) {
        int i = (bid - 8192) * 256 + threadIdx.x;
        int mat = i >> 18;
        int off = i & 262143;
        const float* src = (mat == 0) ? Wq : (mat == 1) ? Wk : (mat == 2) ? Wv : Wo;
        unsigned short* dst = (mat < 3) ? (wqkv + (size_t)mat * 1048576) : wob;
        float4 v = ((const float4*)src)[off];
        ushort4 o;
        o.x = f2bf(v.x); o.y = f2bf(v.y); o.z = f2bf(v.z); o.w = f2bf(v.w);
        ((ushort4*)dst)[off] = o;
    } else {
        int idx = (bid - 12288) * 256 + threadIdx.x;
        int s = idx >> 5;
        int j = idx & 31;
        float invf = powf(10000.0f, -(float)j / 32.0f);
        float ang = (float)s * invf;
        cosT[idx] = cosf(ang);
        sinT[idx] = sinf(ang);
    }
}

// ---------------------------------------------------------------------------
// 256x128-tile 8-wave 8-phase bf16 GEMM + qkv epilogue.
// Main loop is an exact clone of the thrice-verified gemm_out256 schedule
// (only lda differs). Grid 24x32 = 768 blocks = exactly 3 full rounds.
// Epilogue: sec block-uniform; V -> vt transpose store; Q/K -> rope via a
// two-pass post-loop LDS exchange between partner waves (wn even/odd share
// a head; pair (j, j+32) spans the partner's 32-col acc half).
// ---------------------------------------------------------------------------
__global__ __launch_bounds__(512) void gemm128b_qkv(const unsigned short* __restrict__ A,
                                                    const unsigned short* __restrict__ Bm,
                                                    unsigned short* __restrict__ C,
                                                    const float* __restrict__ cosT,
                                                    const float* __restrict__ sinT,
                                                    unsigned short* __restrict__ vt) {
    __shared__ unsigned char smem[98304];
    const int t = threadIdx.x;
    const int l = t & 63;
    const int w = t >> 6;
    const int wm = w >> 2;       // 0..1 -> 128 rows
    const int wn = w & 3;        // 0..3 -> 32 cols
    const int K = DDIM;
    const int NT = K >> 6;

    const int bid = blockIdx.y * gridDim.x + blockIdx.x;
    const int cpx = (gridDim.x * gridDim.y) >> 3;
    const int swz = (bid & 7) * cpx + (bid >> 3);
    const int row0 = (swz / gridDim.x) * 256;
    const int col0 = (swz % gridDim.x) * 128;

    f32x4 acc[8][2];
#pragma unroll
    for (int i = 0; i < 8; ++i)
#pragma unroll
        for (int j = 0; j < 2; ++j) acc[i][j] = f32x4{0.f, 0.f, 0.f, 0.f};

    const unsigned short* aSg = A + (size_t)(row0 + w * 8 + (l >> 3)) * K + ((l & 7) ^ (l >> 3)) * 8;
    const unsigned short* bSg = Bm + (size_t)(col0 + w * 8 + (l >> 3)) * K + ((l & 7) ^ (l >> 3)) * 8;
    const int dRow = (w * 8) * 128;

#define SA(kt, c, buf) \
    gload_lds16(aSg + (size_t)((c) * 64) * K + (kt) * 64, \
                smem + (buf) * 49152 + (c) * 8192 + dRow)
#define SB(kt, c, buf) \
    gload_lds16(bSg + (size_t)((c) * 64) * K + (kt) * 64, \
                smem + (buf) * 49152 + 32768 + (c) * 8192 + dRow)

    SB(0, 0, 0); SB(0, 1, 0);
    SA(0, 0, 0); SA(0, 1, 0); SA(0, 2, 0); SA(0, 3, 0);
    SB(1, 0, 1); SB(1, 1, 1);
    asm volatile("s_waitcnt vmcnt(2)" ::: "memory");
    __builtin_amdgcn_s_barrier();

    const int cA = (l >> 4) << 4;
    const int swr = (l & 7) << 4;
    const int rA0 = wm * 128 + (l & 15);
    const int rB0 = wn * 32 + (l & 15);

    int cur = 0;
    for (int u = 0; u < NT; ++u) {
        const int nxt = cur ^ 1;
        const unsigned char* Ab = smem + cur * 49152;
        const unsigned char* Bb = smem + cur * 49152 + 32768;
        const bool pA = (u + 1 < NT);
        const bool pB = (u + 2 < NT);
        bf16x8 bfr[2][2];

#pragma unroll
        for (int p = 0; p < 4; ++p) {
            if (p == 0) { if (pA) { SA(u + 1, 0, nxt); SA(u + 1, 1, nxt); } }
            if (p == 1) { if (pA) { SA(u + 1, 2, nxt); SA(u + 1, 3, nxt); } }
            if (p == 2) { if (pB) { SB(u + 2, 0, cur); } }
            if (p == 3) { if (pB) { SB(u + 2, 1, cur); } }

            if (p == 0) {
#pragma unroll
                for (int ni = 0; ni < 2; ++ni)
#pragma unroll
                    for (int kk = 0; kk < 2; ++kk) {
                        int row = rB0 + ni * 16;
                        bfr[ni][kk] = *(const bf16x8*)(Bb + (row * 128 + ((kk * 64 + cA) ^ swr)));
                    }
            }
            bf16x8 af[2][2];
#pragma unroll
            for (int m2 = 0; m2 < 2; ++m2)
#pragma unroll
                for (int kk = 0; kk < 2; ++kk) {
                    int row = rA0 + (p * 2 + m2) * 16;
                    af[m2][kk] = *(const bf16x8*)(Ab + (row * 128 + ((kk * 64 + cA) ^ swr)));
                }

            __builtin_amdgcn_s_barrier();
            asm volatile("s_waitcnt lgkmcnt(0)" ::: "memory");
            __builtin_amdgcn_sched_barrier(0);
            __builtin_amdgcn_s_setprio(1);
#pragma unroll
            for (int m2 = 0; m2 < 2; ++m2)
#pragma unroll
                for (int ni = 0; ni < 2; ++ni)
#pragma unroll
                    for (int kk = 0; kk < 2; ++kk)
                        acc[p * 2 + m2][ni] = __builtin_amdgcn_mfma_f32_16x16x32_bf16(
                            af[m2][kk], bfr[ni][kk], acc[p * 2 + m2][ni], 0, 0, 0);
            __builtin_amdgcn_s_setprio(0);
            if (p == 3) {
                if (u < NT - 2) asm volatile("s_waitcnt vmcnt(2)" ::: "memory");
                else            asm volatile("s_waitcnt vmcnt(0)" ::: "memory");
            }
            __builtin_amdgcn_s_barrier();
        }
        cur = nxt;
    }
#undef SA
#undef SB

    // ---- epilogue (sec is block-uniform: col0 is a multiple of 128)
    const int cr = (l >> 4) << 2;
    const int cc = l & 15;
    const int sec = col0 >> 10;   // 0:Q 1:K 2:V

    if (sec == 2) {
        // V: transposed store vt[((b*HH+h)*HD+d)*SS + s], packed ushort4
#pragma unroll
        for (int mi = 0; mi < 8; ++mi) {
            int s0 = row0 + wm * 128 + mi * 16 + cr;
            int bI = s0 >> 11;
            int sI = s0 & (SS - 1);
#pragma unroll
            for (int ni = 0; ni < 2; ++ni) {
                int vcol = col0 + wn * 32 + ni * 16 + cc - 2048;
                int hh = vcol >> 6, dd = vcol & 63;
                ushort4 o;
                o.x = f2bf(acc[mi][ni][0]);
                o.y = f2bf(acc[mi][ni][1]);
                o.z = f2bf(acc[mi][ni][2]);
                o.w = f2bf(acc[mi][ni][3]);
                *(ushort4*)&vt[((size_t)((bI * HH + hh) * HD + dd)) * SS + sI] = o;
            }
        }
    } else {
        // Q/K rope: two-pass partner-wave exchange (wn^1 owns the other
        // 32-col half of this head). All loop gloads drained (vmcnt(0)) and
        // barriered, so smem is dead scratch here.
        const float qs = (sec == 0) ? QSCALE : 1.0f;
        const int pw = w ^ 1;
        const bool hiHalf = (wn & 1);
#pragma unroll
        for (int pass = 0; pass < 2; ++pass) {
            __syncthreads();
            // write my 64-row x 32-col f32 quarter to smem[w*8192]
#pragma unroll
            for (int m4 = 0; m4 < 4; ++m4)
#pragma unroll
                for (int ni = 0; ni < 2; ++ni)
#pragma unroll
                    for (int r = 0; r < 4; ++r)
                        *(float*)(smem + w * 8192 +
                                  ((m4 * 16 + cr + r) * 128 + (ni * 16 + cc) * 4)) =
                            acc[pass * 4 + m4][ni][r];
            __syncthreads();
#pragma unroll
            for (int m4 = 0; m4 < 4; ++m4) {
#pragma unroll
                for (int r = 0; r < 4; ++r) {
                    int rr = m4 * 16 + cr + r;
                    int grow = row0 + wm * 128 + pass * 64 + rr;
                    int s = grow & (SS - 1);
#pragma unroll
                    for (int ni = 0; ni < 2; ++ni) {
                        int lc = ni * 16 + cc;
                        float mine = acc[pass * 4 + m4][ni][r];
                        float other = *(const float*)(smem + pw * 8192 + (rr * 128 + lc * 4));
                        float c = cosT[(s << 5) + lc];
                        float sn = sinT[(s << 5) + lc];
                        float o = hiHalf ? (mine * c + other * sn) : (mine * c - other * sn);
                        C[(size_t)grow * QKVLD + col0 + wn * 32 + lc] = f2bf(o * qs);
                    }
                }
            }
        }
    }
}

// ---------------------------------------------------------------------------
// 256x128-tile 8-wave 8-phase bf16 GEMM, f32 C — output projection.
// (verified rounds 13,15,16; 256 blocks = 1 full round)
// ---------------------------------------------------------------------------
__global__ __launch_bounds__(512) void gemm_out256(const unsigned short* __restrict__ A,
                                                   const unsigned short* __restrict__ Bm,
                                                   float* __restrict__ C) {
    __shared__ unsigned char smem[98304];
    const int t = threadIdx.x;
    const int l = t & 63;
    const int w = t >> 6;
    const int wm = w >> 2;
    const int wn = w & 3;
    const int K = DDIM;
    const int NT = K >> 6;

    const int bid = blockIdx.y * gridDim.x + blockIdx.x;
    const int cpx = (gridDim.x * gridDim.y) >> 3;
    const int swz = (bid & 7) * cpx + (bid >> 3);
    const int row0 = (swz / gridDim.x) * 256;
    const int col0 = (swz % gridDim.x) * 128;

    f32x4 acc[8][2];
#pragma unroll
    for (int i = 0; i < 8; ++i)
#pragma unroll
        for (int j = 0; j < 2; ++j) acc[i][j] = f32x4{0.f, 0.f, 0.f, 0.f};

    const unsigned short* aSg = A + (size_t)(row0 + w * 8 + (l >> 3)) * QKVLD + ((l & 7) ^ (l >> 3)) * 8;
    const unsigned short* bSg = Bm + (size_t)(col0 + w * 8 + (l >> 3)) * K + ((l & 7) ^ (l >> 3)) * 8;
    const int dRow = (w * 8) * 128;

#define SA(kt, c, buf) \
    gload_lds16(aSg + (size_t)((c) * 64) * QKVLD + (kt) * 64, \
                smem + (buf) * 49152 + (c) * 8192 + dRow)
#define SB(kt, c, buf) \
    gload_lds16(bSg + (size_t)((c) * 64) * K + (kt) * 64, \
                smem + (buf) * 49152 + 32768 + (c) * 8192 + dRow)

    SB(0, 0, 0); SB(0, 1, 0);
    SA(0, 0, 0); SA(0, 1, 0); SA(0, 2, 0); SA(0, 3, 0);
    SB(1, 0, 1); SB(1, 1, 1);
    asm volatile("s_waitcnt vmcnt(2)" ::: "memory");
    __builtin_amdgcn_s_barrier();

    const int cA = (l >> 4) << 4;
    const int swr = (l & 7) << 4;
    const int rA0 = wm * 128 + (l & 15);
    const int rB0 = wn * 32 + (l & 15);

    int cur = 0;
    for (int u = 0; u < NT; ++u) {
        const int nxt = cur ^ 1;
        const unsigned char* Ab = smem + cur * 49152;
        const unsigned char* Bb = smem + cur * 49152 + 32768;
        const bool pA = (u + 1 < NT);
        const bool pB = (u + 2 < NT);
        bf16x8 bfr[2][2];

#pragma unroll
        for (int p = 0; p < 4; ++p) {
            if (p == 0) { if (pA) { SA(u + 1, 0, nxt); SA(u + 1, 1, nxt); } }
            if (p == 1) { if (pA) { SA(u + 1, 2, nxt); SA(u + 1, 3, nxt); } }
            if (p == 2) { if (pB) { SB(u + 2, 0, cur); } }
            if (p == 3) { if (pB) { SB(u + 2, 1, cur); } }

            if (p == 0) {
#pragma unroll
                for (int ni = 0; ni < 2; ++ni)
#pragma unroll
                    for (int kk = 0; kk < 2; ++kk) {
                        int row = rB0 + ni * 16;
                        bfr[ni][kk] = *(const bf16x8*)(Bb + (row * 128 + ((kk * 64 + cA) ^ swr)));
                    }
            }
            bf16x8 af[2][2];
#pragma unroll
            for (int m2 = 0; m2 < 2; ++m2)
#pragma unroll
                for (int kk = 0; kk < 2; ++kk) {
                    int row = rA0 + (p * 2 + m2) * 16;
                    af[m2][kk] = *(const bf16x8*)(Ab + (row * 128 + ((kk * 64 + cA) ^ swr)));
                }

            __builtin_amdgcn_s_barrier();
            asm volatile("s_waitcnt lgkmcnt(0)" ::: "memory");
            __builtin_amdgcn_sched_barrier(0);
            __builtin_amdgcn_s_setprio(1);
#pragma unroll
            for (int m2 = 0; m2 < 2; ++m2)
#pragma unroll
                for (int ni = 0; ni < 2; ++ni)
#pragma unroll
                    for (int kk = 0; kk < 2; ++kk)
                        acc[p * 2 + m2][ni] = __builtin_amdgcn_mfma_f32_16x16x32_bf16(
                            af[m2][kk], bfr[ni][kk], acc[p * 2 + m2][ni], 0, 0, 0);
            __builtin_amdgcn_s_setprio(0);
            if (p == 3) {
                if (u < NT - 2) asm volatile("s_waitcnt vmcnt(2)" ::: "memory");
                else            asm volatile("s_waitcnt vmcnt(0)" ::: "memory");
            }
            __builtin_amdgcn_s_barrier();
        }
        cur = nxt;
    }
#undef SA
#undef SB

    const int cr = (l >> 4) << 2;
    const int cc = l & 15;
#pragma unroll
    for (int mi = 0; mi < 8; ++mi)
#pragma unroll
        for (int ni = 0; ni < 2; ++ni) {
            int gcol = col0 + wn * 32 + ni * 16 + cc;
#pragma unroll
            for (int r = 0; r < 4; ++r) {
                int grow = row0 + wm * 128 + mi * 16 + cr + r;
                C[(size_t)grow * DDIM + gcol] = acc[mi][ni][r];
            }
        }
}

// ---------------------------------------------------------------------------
// MFMA flash attention v12 (verified round 16): 8 waves/block, 256 q-rows,
// grid 512 = 2 blocks/CU, XCD-locality remap, no-max exp2 softmax.
// ---------------------------------------------------------------------------
__global__ __launch_bounds__(512) void attn_mfma12(const unsigned short* __restrict__ qkv,
                                                   const unsigned short* __restrict__ vt,
                                                   unsigned short* __restrict__ og) {
    __shared__ unsigned char smem[32768];
    const int tid = threadIdx.x;
    const int ln = tid & 63;
    const int w = tid >> 6;        // 0..7
    const int lq = ln & 31;
    const int hi = ln >> 5;

    const int did = blockIdx.x;
    const int b = did & 3;
    const int h = (did >> 2) & 15;
    const int qb0 = (did >> 6) << 8;   // 256 q-rows per block

    const int headoff = h * HD;
    const size_t bS = (size_t)b * SS;

    bf16x8 qf[4];
    {
        const unsigned short* qsrc = qkv + (bS + qb0 + w * 32 + lq) * QKVLD + headoff + hi * 8;
#pragma unroll
        for (int dc = 0; dc < 4; ++dc)
            qf[dc] = *(const bf16x8*)(qsrc + dc * 16);
    }

    f32x16 oacc[2];
#pragma unroll
    for (int i = 0; i < 2; ++i)
#pragma unroll
        for (int r = 0; r < 16; ++r) oacc[i][r] = 0.f;
    float lsum = 0.f;

    f32x16 fzero;
#pragma unroll
    for (int r = 0; r < 16; ++r) fzero[r] = 0.f;

    const int srow = w * 8 + (ln >> 3);
    const int scol = ((ln & 7) ^ (ln >> 3)) << 3;
    const unsigned short* kbase_g = qkv + bS * QKVLD + 1024 + headoff;
    const unsigned short* vtbase_g = vt + (size_t)(b * HH + h) * HD * SS;

    {
        gload_lds16(kbase_g + (size_t)srow * QKVLD + scol, smem + w * 1024);
        gload_lds16(vtbase_g + (size_t)srow * SS + scol,   smem + 16384 + w * 1024);
    }
    __syncthreads();

#pragma unroll 2
    for (int tkv = 0; tkv < SS / 64; ++tkv) {
        const int cur = tkv & 1;
        const int kcur = cur * 8192;
        const int vcur = 16384 + cur * 8192;
        const int nxt = cur ^ 1;
        const bool pre = (tkv + 1 < SS / 64);
        if (pre) {
            const int kv1 = (tkv + 1) * 64;
            gload_lds16(kbase_g + (size_t)(kv1 + srow) * QKVLD + scol,
                        smem + nxt * 8192 + w * 1024);
            gload_lds16(vtbase_g + (size_t)srow * SS + kv1 + scol,
                        smem + 16384 + nxt * 8192 + w * 1024);
        }

        f32x16 st[2];
#pragma unroll
        for (int kb = 0; kb < 2; ++kb) {
            bf16x8 kf[4];
#pragma unroll
            for (int dc = 0; dc < 4; ++dc) {
                int row = kb * 32 + lq;
                int o = kcur + ((row * 128 + dc * 32 + hi * 16) ^ ((row & 7) << 4));
                kf[dc] = *(const bf16x8*)(smem + o);
            }
            __builtin_amdgcn_s_setprio(1);
            st[kb] = __builtin_amdgcn_mfma_f32_32x32x16_bf16(kf[0], qf[0], fzero, 0, 0, 0);
#pragma unroll
            for (int dc = 1; dc < 4; ++dc)
                st[kb] = __builtin_amdgcn_mfma_f32_32x32x16_bf16(kf[dc], qf[dc], st[kb], 0, 0, 0);
            __builtin_amdgcn_s_setprio(0);
        }

        float pg[32];
#pragma unroll
        for (int j = 0; j < 16; ++j) pg[j] = __builtin_amdgcn_exp2f(st[0][j]);
#pragma unroll
        for (int j = 0; j < 16; ++j) pg[16 + j] = __builtin_amdgcn_exp2f(st[1][j]);

        i32x4 pwv[4];
#pragma unroll
        for (int g = 0; g < 4; ++g) {
            unsigned u0, u1, u2, u3;
            asm("v_cvt_pk_bf16_f32 %0, %1, %2" : "=v"(u0) : "v"(pg[g * 8 + 0]), "v"(pg[g * 8 + 1]));
            asm("v_cvt_pk_bf16_f32 %0, %1, %2" : "=v"(u1) : "v"(pg[g * 8 + 2]), "v"(pg[g * 8 + 3]));
            asm("v_cvt_pk_bf16_f32 %0, %1, %2" : "=v"(u2) : "v"(pg[g * 8 + 4]), "v"(pg[g * 8 + 5]));
            asm("v_cvt_pk_bf16_f32 %0, %1, %2" : "=v"(u3) : "v"(pg[g * 8 + 6]), "v"(pg[g * 8 + 7]));
            asm("v_permlane32_swap_b32 %0, %1" : "+v"(u0), "+v"(u2));
            asm("v_permlane32_swap_b32 %0, %1" : "+v"(u1), "+v"(u3));
            pwv[g][0] = (int)u0; pwv[g][1] = (int)u1; pwv[g][2] = (int)u2; pwv[g][3] = (int)u3;
        }

        float rs;
        {
            float s0 = (pg[0] + pg[1]) + (pg[2] + pg[3]);
            float s1 = (pg[4] + pg[5]) + (pg[6] + pg[7]);
            float s2 = (pg[8] + pg[9]) + (pg[10] + pg[11]);
            float s3 = (pg[12] + pg[13]) + (pg[14] + pg[15]);
            float s4 = (pg[16] + pg[17]) + (pg[18] + pg[19]);
            float s5 = (pg[20] + pg[21]) + (pg[22] + pg[23]);
            float s6 = (pg[24] + pg[25]) + (pg[26] + pg[27]);
            float s7 = (pg[28] + pg[29]) + (pg[30] + pg[31]);
            rs = ((s0 + s1) + (s2 + s3)) + ((s4 + s5) + (s6 + s7));
        }
        rs += __shfl_xor(rs, 32);
        lsum += rs;

        __builtin_amdgcn_s_setprio(1);
#pragma unroll
        for (int dblk = 0; dblk < 2; ++dblk) {
#pragma unroll
            for (int ks = 0; ks < 4; ++ks) {
                int row = dblk * 32 + lq;
                int o = vcur + ((row * 128 + ks * 32 + hi * 16) ^ ((row & 7) << 4));
                bf16x8 vf = *(const bf16x8*)(smem + o);
                oacc[dblk] = __builtin_amdgcn_mfma_f32_32x32x16_bf16(
                    __builtin_bit_cast(bf16x8, pwv[ks]), vf, oacc[dblk], 0, 0, 0);
            }
        }
        __builtin_amdgcn_s_setprio(0);

        __syncthreads();
    }

    {
        float inv = 1.0f / lsum;
#pragma unroll
        for (int r = 0; r < 16; ++r) {
            int crow = (r & 3) + 8 * (r >> 2) + 4 * hi;
            float invr = __shfl(inv, crow);
            int grow = qb0 + w * 32 + crow;
            size_t base = (bS + grow) * QKVLD + headoff + lq;
            og[base]      = f2bf(oacc[0][r] * invr);
            og[base + 32] = f2bf(oacc[1][r] * invr);
        }
    }
}

// ---------------------------------------------------------------------------
extern "C" void kernel_launch(void* const* d_in, const int* in_sizes, int n_in,
                              void* d_out, int out_size, void* d_ws, size_t ws_size,
                              hipStream_t stream) {
    const float* x  = (const float*)d_in[0];
    const float* Wq = (const float*)d_in[1];
    const float* Wk = (const float*)d_in[2];
    const float* Wv = (const float*)d_in[3];
    const float* Wo = (const float*)d_in[4];
    float* out = (float*)d_out;

    const size_t BSD = (size_t)BB * SS * DDIM;     // 8388608
    const size_t WSZ = (size_t)DDIM * DDIM;        // 1048576

    unsigned short* xb   = (unsigned short*)d_ws;          // [8192][1024]
    unsigned short* wqkv = xb + BSD;                       // [3072][1024]
    unsigned short* wob  = wqkv + 3 * WSZ;                 // [1024][1024]
    unsigned short* qkv  = wob + WSZ;                      // [8192][3072]
    unsigned short* vt   = qkv + (size_t)BB * SS * QKVLD;  // [B][H][64][2048]
    float* cosT = (float*)(vt + BSD);
    float* sinT = cosT + (size_t)SS * 32;

    // merged prep: x-cvt (8192) + W-cvt (4096) + rope table (256)
    hipLaunchKernelGGL(prep_all, dim3(12544), dim3(256), 0, stream,
                       x, Wq, Wk, Wv, Wo, xb, wqkv, wob, cosT, sinT);

    // fused QKV projection: 256x128-tile 8-phase (gemm_out256 clone),
    // 768 blocks = exactly 3 full rounds; rope/V-transpose epilogue
    hipLaunchKernelGGL(gemm128b_qkv, dim3(QKVLD / 128, BB * SS / 256), dim3(512), 0, stream,
                       xb, wqkv, qkv, cosT, sinT, vt);

    // attention: 8 waves/block, 256 q-rows, grid 512 = 2 blocks/CU exactly
    hipLaunchKernelGGL(attn_mfma12, dim3(512), dim3(512), 0, stream, qkv, vt, qkv);

    // output projection: 256x128-tile 8-phase, 256 blocks = 1 full round
    hipLaunchKernelGGL(gemm_out256, dim3(DDIM / 128, BB * SS / 256), dim3(512), 0, stream,
                       qkv, wob, out);
}

// Round 18
// 180.364 us; speedup vs baseline: 1.0204x; 1.0204x over previous
//
#include <hip/hip_runtime.h>
#include <math.h>
#include <stdint.h>

#define BB 4
#define SS 2048
#define DDIM 1024
#define HH 16
#define HD 64
#define QKVLD 3072
#define QSCALE (0.125f * 1.44269504089f)

typedef __bf16 bf16x8 __attribute__((ext_vector_type(8)));
typedef float f32x4 __attribute__((ext_vector_type(4)));
typedef float f32x16 __attribute__((ext_vector_type(16)));
typedef int i32x4 __attribute__((ext_vector_type(4)));

// ---------------- helpers ----------------
__device__ __forceinline__ unsigned short f2bf(float f) {
    union { float f; unsigned u; } v; v.f = f;
    unsigned r = (v.u + 0x7FFFu + ((v.u >> 16) & 1u)) >> 16;
    return (unsigned short)r;
}
__device__ __forceinline__ void gload_lds16(const unsigned short* g, unsigned char* s) {
    __builtin_amdgcn_global_load_lds(
        (const __attribute__((address_space(1))) unsigned int*)(g),
        (__attribute__((address_space(3))) unsigned int*)(s), 16, 0, 0);
}

// ---------------------------------------------------------------------------
// Merged prep: x -> bf16 (8192 blks), W4 -> bf16 (4096 blks), rope table (256)
// ---------------------------------------------------------------------------
__global__ void prep_all(const float* __restrict__ x,
                         const float* __restrict__ Wq, const float* __restrict__ Wk,
                         const float* __restrict__ Wv, const float* __restrict__ Wo,
                         unsigned short* __restrict__ xb,
                         unsigned short* __restrict__ wqkv, unsigned short* __restrict__ wob,
                         float* __restrict__ cosT, float* __restrict__ sinT) {
    int bid = blockIdx.x;
    if (bid < 8192) {
        int i = bid * 256 + threadIdx.x;
        float4 v = ((const float4*)x)[i];
        ushort4 o;
        o.x = f2bf(v.x); o.y = f2bf(v.y); o.z = f2bf(v.z); o.w = f2bf(v.w);
        ((ushort4*)xb)[i] = o;
    } else if (bid < 12288) {
        int i = (bid - 8192) * 256 + threadIdx.x;
        int mat = i >> 18;
        int off = i & 262143;
        const float* src = (mat == 0) ? Wq : (mat == 1) ? Wk : (mat == 2) ? Wv : Wo;
        unsigned short* dst = (mat < 3) ? (wqkv + (size_t)mat * 1048576) : wob;
        float4 v = ((const float4*)src)[off];
        ushort4 o;
        o.x = f2bf(v.x); o.y = f2bf(v.y); o.z = f2bf(v.z); o.w = f2bf(v.w);
        ((ushort4*)dst)[off] = o;
    } else {
        int idx = (bid - 12288) * 256 + threadIdx.x;
        int s = idx >> 5;
        int j = idx & 31;
        float invf = powf(10000.0f, -(float)j / 32.0f);
        float ang = (float)s * invf;
        cosT[idx] = cosf(ang);
        sinT[idx] = sinf(ang);
    }
}

// ---------------------------------------------------------------------------
// 256x256 8-wave 8-phase bf16 GEMM, qkv epilogue (verified rounds 12-13,15-16)
// ---------------------------------------------------------------------------
__global__ __launch_bounds__(512) void gemm256_qkv(const unsigned short* __restrict__ A,
                                                   const unsigned short* __restrict__ Bm,
                                                   unsigned short* __restrict__ C,
                                                   const float* __restrict__ cosT,
                                                   const float* __restrict__ sinT,
                                                   unsigned short* __restrict__ vt) {
    __shared__ unsigned char smem[131072];
    const int t = threadIdx.x;
    const int l = t & 63;
    const int w = t >> 6;
    const int wm = w >> 2;
    const int wn = w & 3;
    const int K = DDIM;
    const int NT = K >> 6;

    const int bid = blockIdx.y * gridDim.x + blockIdx.x;
    const int cpx = (gridDim.x * gridDim.y) >> 3;
    const int swz = (bid & 7) * cpx + (bid >> 3);
    const int row0 = (swz / gridDim.x) * 256;
    const int col0 = (swz % gridDim.x) * 256;

    f32x4 acc[8][4];
#pragma unroll
    for (int i = 0; i < 8; ++i)
#pragma unroll
        for (int j = 0; j < 4; ++j) acc[i][j] = f32x4{0.f, 0.f, 0.f, 0.f};

    const unsigned short* aSg = A + (size_t)(row0 + w * 16 + (l >> 3)) * K + ((l & 7) ^ (l >> 3)) * 8;
    const unsigned short* bSg = Bm + (size_t)(col0 + w * 16 + (l >> 3)) * K + ((l & 7) ^ (l >> 3)) * 8;
    const int dRow = (w * 16) * 128;

#define STAGE_A(kt, h, j, buf) \
    gload_lds16(aSg + (size_t)((h) * 128 + (j) * 8) * K + (kt) * 64, \
                smem + (buf) * 65536 + (h) * 16384 + dRow + (j) * 1024)
#define STAGE_B(kt, h, j, buf) \
    gload_lds16(bSg + (size_t)((h) * 128 + (j) * 8) * K + (kt) * 64, \
                smem + (buf) * 65536 + 32768 + (h) * 16384 + dRow + (j) * 1024)

    STAGE_B(0, 0, 0, 0); STAGE_B(0, 0, 1, 0); STAGE_B(0, 1, 0, 0); STAGE_B(0, 1, 1, 0);
    STAGE_A(0, 0, 0, 0); STAGE_A(0, 0, 1, 0); STAGE_A(0, 1, 0, 0); STAGE_A(0, 1, 1, 0);
    STAGE_B(1, 0, 0, 1); STAGE_B(1, 0, 1, 1); STAGE_B(1, 1, 0, 1); STAGE_B(1, 1, 1, 1);
    asm volatile("s_waitcnt vmcnt(4)" ::: "memory");
    __builtin_amdgcn_s_barrier();

    const int cA = (l >> 4) << 4;
    const int swr = (l & 7) << 4;
    const int rA0 = wm * 128 + (l & 15);
    const int rB0 = wn * 64 + (l & 15);

    int cur = 0;
    for (int u = 0; u < NT; ++u) {
        const int nxt = cur ^ 1;
        const unsigned char* Ab = smem + cur * 65536;
        const unsigned char* Bb = smem + cur * 65536 + 32768;
        const bool pA = (u + 1 < NT);
        const bool pB = (u + 2 < NT);
        bf16x8 bfr[4][2];

#pragma unroll
        for (int p = 0; p < 4; ++p) {
            if (p == 0) { if (pA) { STAGE_A(u + 1, 0, 0, nxt); STAGE_A(u + 1, 0, 1, nxt); } }
            if (p == 1) { if (pA) { STAGE_A(u + 1, 1, 0, nxt); STAGE_A(u + 1, 1, 1, nxt); } }
            if (p == 2) { if (pB) { STAGE_B(u + 2, 0, 0, cur); STAGE_B(u + 2, 0, 1, cur); } }
            if (p == 3) { if (pB) { STAGE_B(u + 2, 1, 0, cur); STAGE_B(u + 2, 1, 1, cur); } }

            if (p == 0) {
#pragma unroll
                for (int ni = 0; ni < 4; ++ni)
#pragma unroll
                    for (int kk = 0; kk < 2; ++kk) {
                        int row = rB0 + ni * 16;
                        bfr[ni][kk] = *(const bf16x8*)(Bb + (row * 128 + ((kk * 64 + cA) ^ swr)));
                    }
            }
            bf16x8 af[2][2];
#pragma unroll
            for (int m2 = 0; m2 < 2; ++m2)
#pragma unroll
                for (int kk = 0; kk < 2; ++kk) {
                    int row = rA0 + (p * 2 + m2) * 16;
                    af[m2][kk] = *(const bf16x8*)(Ab + (row * 128 + ((kk * 64 + cA) ^ swr)));
                }

            __builtin_amdgcn_s_barrier();
            asm volatile("s_waitcnt lgkmcnt(0)" ::: "memory");
            __builtin_amdgcn_sched_barrier(0);
            __builtin_amdgcn_s_setprio(1);
#pragma unroll
            for (int m2 = 0; m2 < 2; ++m2)
#pragma unroll
                for (int ni = 0; ni < 4; ++ni)
#pragma unroll
                    for (int kk = 0; kk < 2; ++kk)
                        acc[p * 2 + m2][ni] = __builtin_amdgcn_mfma_f32_16x16x32_bf16(
                            af[m2][kk], bfr[ni][kk], acc[p * 2 + m2][ni], 0, 0, 0);
            __builtin_amdgcn_s_setprio(0);
            if (p == 3) {
                if (u < NT - 2) asm volatile("s_waitcnt vmcnt(4)" ::: "memory");
                else            asm volatile("s_waitcnt vmcnt(0)" ::: "memory");
            }
            __builtin_amdgcn_s_barrier();
        }
        cur = nxt;
    }
#undef STAGE_A
#undef STAGE_B

    const int cr = (l >> 4) << 2;
    const int cc = l & 15;
    const int sec = (col0 + wn * 64) >> 10;

    if (sec == 2) {
#pragma unroll
        for (int mi = 0; mi < 8; ++mi) {
            int s0 = row0 + wm * 128 + mi * 16 + cr;
            int bI = s0 >> 11;
            int sI = s0 & (SS - 1);
#pragma unroll
            for (int ni = 0; ni < 4; ++ni) {
                int vcol = col0 + wn * 64 + ni * 16 + cc - 2048;
                int hh = vcol >> 6, dd = vcol & 63;
                ushort4 o;
                o.x = f2bf(acc[mi][ni][0]);
                o.y = f2bf(acc[mi][ni][1]);
                o.z = f2bf(acc[mi][ni][2]);
                o.w = f2bf(acc[mi][ni][3]);
                *(ushort4*)&vt[((size_t)((bI * HH + hh) * HD + dd)) * SS + sI] = o;
            }
        }
    } else {
        const float qs = (sec == 0) ? QSCALE : 1.0f;
#pragma unroll
        for (int mi = 0; mi < 8; ++mi) {
#pragma unroll
            for (int r = 0; r < 4; ++r) {
                int grow = row0 + wm * 128 + mi * 16 + cr + r;
                int s = grow & (SS - 1);
#pragma unroll
                for (int ni = 0; ni < 2; ++ni) {
                    int j = ni * 16 + cc;
                    float c = cosT[(s << 5) + j];
                    float sn = sinT[(s << 5) + j];
                    float x1 = acc[mi][ni][r], x2 = acc[mi][ni + 2][r];
                    int gcol = col0 + wn * 64 + j;
                    C[(size_t)grow * QKVLD + gcol]      = f2bf((x1 * c - x2 * sn) * qs);
                    C[(size_t)grow * QKVLD + gcol + 32] = f2bf((x2 * c + x1 * sn) * qs);
                }
            }
        }
    }
}

// ---------------------------------------------------------------------------
// 256x128-tile 8-wave 8-phase bf16 GEMM, f32 C — output projection.
// (verified rounds 13,15,16; 256 blocks = 1 full round)
// ---------------------------------------------------------------------------
__global__ __launch_bounds__(512) void gemm_out256(const unsigned short* __restrict__ A,
                                                   const unsigned short* __restrict__ Bm,
                                                   float* __restrict__ C) {
    __shared__ unsigned char smem[98304];
    const int t = threadIdx.x;
    const int l = t & 63;
    const int w = t >> 6;
    const int wm = w >> 2;
    const int wn = w & 3;
    const int K = DDIM;
    const int NT = K >> 6;

    const int bid = blockIdx.y * gridDim.x + blockIdx.x;
    const int cpx = (gridDim.x * gridDim.y) >> 3;
    const int swz = (bid & 7) * cpx + (bid >> 3);
    const int row0 = (swz / gridDim.x) * 256;
    const int col0 = (swz % gridDim.x) * 128;

    f32x4 acc[8][2];
#pragma unroll
    for (int i = 0; i < 8; ++i)
#pragma unroll
        for (int j = 0; j < 2; ++j) acc[i][j] = f32x4{0.f, 0.f, 0.f, 0.f};

    const unsigned short* aSg = A + (size_t)(row0 + w * 8 + (l >> 3)) * QKVLD + ((l & 7) ^ (l >> 3)) * 8;
    const unsigned short* bSg = Bm + (size_t)(col0 + w * 8 + (l >> 3)) * K + ((l & 7) ^ (l >> 3)) * 8;
    const int dRow = (w * 8) * 128;

#define SA(kt, c, buf) \
    gload_lds16(aSg + (size_t)((c) * 64) * QKVLD + (kt) * 64, \
                smem + (buf) * 49152 + (c) * 8192 + dRow)
#define SB(kt, c, buf) \
    gload_lds16(bSg + (size_t)((c) * 64) * K + (kt) * 64, \
                smem + (buf) * 49152 + 32768 + (c) * 8192 + dRow)

    SB(0, 0, 0); SB(0, 1, 0);
    SA(0, 0, 0); SA(0, 1, 0); SA(0, 2, 0); SA(0, 3, 0);
    SB(1, 0, 1); SB(1, 1, 1);
    asm volatile("s_waitcnt vmcnt(2)" ::: "memory");
    __builtin_amdgcn_s_barrier();

    const int cA = (l >> 4) << 4;
    const int swr = (l & 7) << 4;
    const int rA0 = wm * 128 + (l & 15);
    const int rB0 = wn * 32 + (l & 15);

    int cur = 0;
    for (int u = 0; u < NT; ++u) {
        const int nxt = cur ^ 1;
        const unsigned char* Ab = smem + cur * 49152;
        const unsigned char* Bb = smem + cur * 49152 + 32768;
        const bool pA = (u + 1 < NT);
        const bool pB = (u + 2 < NT);
        bf16x8 bfr[2][2];

#pragma unroll
        for (int p = 0; p < 4; ++p) {
            if (p == 0) { if (pA) { SA(u + 1, 0, nxt); SA(u + 1, 1, nxt); } }
            if (p == 1) { if (pA) { SA(u + 1, 2, nxt); SA(u + 1, 3, nxt); } }
            if (p == 2) { if (pB) { SB(u + 2, 0, cur); } }
            if (p == 3) { if (pB) { SB(u + 2, 1, cur); } }

            if (p == 0) {
#pragma unroll
                for (int ni = 0; ni < 2; ++ni)
#pragma unroll
                    for (int kk = 0; kk < 2; ++kk) {
                        int row = rB0 + ni * 16;
                        bfr[ni][kk] = *(const bf16x8*)(Bb + (row * 128 + ((kk * 64 + cA) ^ swr)));
                    }
            }
            bf16x8 af[2][2];
#pragma unroll
            for (int m2 = 0; m2 < 2; ++m2)
#pragma unroll
                for (int kk = 0; kk < 2; ++kk) {
                    int row = rA0 + (p * 2 + m2) * 16;
                    af[m2][kk] = *(const bf16x8*)(Ab + (row * 128 + ((kk * 64 + cA) ^ swr)));
                }

            __builtin_amdgcn_s_barrier();
            asm volatile("s_waitcnt lgkmcnt(0)" ::: "memory");
            __builtin_amdgcn_sched_barrier(0);
            __builtin_amdgcn_s_setprio(1);
#pragma unroll
            for (int m2 = 0; m2 < 2; ++m2)
#pragma unroll
                for (int ni = 0; ni < 2; ++ni)
#pragma unroll
                    for (int kk = 0; kk < 2; ++kk)
                        acc[p * 2 + m2][ni] = __builtin_amdgcn_mfma_f32_16x16x32_bf16(
                            af[m2][kk], bfr[ni][kk], acc[p * 2 + m2][ni], 0, 0, 0);
            __builtin_amdgcn_s_setprio(0);
            if (p == 3) {
                if (u < NT - 2) asm volatile("s_waitcnt vmcnt(2)" ::: "memory");
                else            asm volatile("s_waitcnt vmcnt(0)" ::: "memory");
            }
            __builtin_amdgcn_s_barrier();
        }
        cur = nxt;
    }
#undef SA
#undef SB

    const int cr = (l >> 4) << 2;
    const int cc = l & 15;
#pragma unroll
    for (int mi = 0; mi < 8; ++mi)
#pragma unroll
        for (int ni = 0; ni < 2; ++ni) {
            int gcol = col0 + wn * 32 + ni * 16 + cc;
#pragma unroll
            for (int r = 0; r < 4; ++r) {
                int grow = row0 + wm * 128 + mi * 16 + cr + r;
                C[(size_t)grow * DDIM + gcol] = acc[mi][ni][r];
            }
        }
}

// ---------------------------------------------------------------------------
// MFMA flash attention v12 (verified round 16): 8 waves/block, 256 q-rows,
// grid 512 = 2 blocks/CU, XCD-locality remap, no-max exp2 softmax.
// ---------------------------------------------------------------------------
__global__ __launch_bounds__(512) void attn_mfma12(const unsigned short* __restrict__ qkv,
                                                   const unsigned short* __restrict__ vt,
                                                   unsigned short* __restrict__ og) {
    __shared__ unsigned char smem[32768];
    const int tid = threadIdx.x;
    const int ln = tid & 63;
    const int w = tid >> 6;        // 0..7
    const int lq = ln & 31;
    const int hi = ln >> 5;

    const int did = blockIdx.x;
    const int b = did & 3;
    const int h = (did >> 2) & 15;
    const int qb0 = (did >> 6) << 8;   // 256 q-rows per block

    const int headoff = h * HD;
    const size_t bS = (size_t)b * SS;

    bf16x8 qf[4];
    {
        const unsigned short* qsrc = qkv + (bS + qb0 + w * 32 + lq) * QKVLD + headoff + hi * 8;
#pragma unroll
        for (int dc = 0; dc < 4; ++dc)
            qf[dc] = *(const bf16x8*)(qsrc + dc * 16);
    }

    f32x16 oacc[2];
#pragma unroll
    for (int i = 0; i < 2; ++i)
#pragma unroll
        for (int r = 0; r < 16; ++r) oacc[i][r] = 0.f;
    float lsum = 0.f;

    f32x16 fzero;
#pragma unroll
    for (int r = 0; r < 16; ++r) fzero[r] = 0.f;

    const int srow = w * 8 + (ln >> 3);
    const int scol = ((ln & 7) ^ (ln >> 3)) << 3;
    const unsigned short* kbase_g = qkv + bS * QKVLD + 1024 + headoff;
    const unsigned short* vtbase_g = vt + (size_t)(b * HH + h) * HD * SS;

    {
        gload_lds16(kbase_g + (size_t)srow * QKVLD + scol, smem + w * 1024);
        gload_lds16(vtbase_g + (size_t)srow * SS + scol,   smem + 16384 + w * 1024);
    }
    __syncthreads();

#pragma unroll 2
    for (int tkv = 0; tkv < SS / 64; ++tkv) {
        const int cur = tkv & 1;
        const int kcur = cur * 8192;
        const int vcur = 16384 + cur * 8192;
        const int nxt = cur ^ 1;
        const bool pre = (tkv + 1 < SS / 64);
        if (pre) {
            const int kv1 = (tkv + 1) * 64;
            gload_lds16(kbase_g + (size_t)(kv1 + srow) * QKVLD + scol,
                        smem + nxt * 8192 + w * 1024);
            gload_lds16(vtbase_g + (size_t)srow * SS + kv1 + scol,
                        smem + 16384 + nxt * 8192 + w * 1024);
        }

        f32x16 st[2];
#pragma unroll
        for (int kb = 0; kb < 2; ++kb) {
            bf16x8 kf[4];
#pragma unroll
            for (int dc = 0; dc < 4; ++dc) {
                int row = kb * 32 + lq;
                int o = kcur + ((row * 128 + dc * 32 + hi * 16) ^ ((row & 7) << 4));
                kf[dc] = *(const bf16x8*)(smem + o);
            }
            __builtin_amdgcn_s_setprio(1);
            st[kb] = __builtin_amdgcn_mfma_f32_32x32x16_bf16(kf[0], qf[0], fzero, 0, 0, 0);
#pragma unroll
            for (int dc = 1; dc < 4; ++dc)
                st[kb] = __builtin_amdgcn_mfma_f32_32x32x16_bf16(kf[dc], qf[dc], st[kb], 0, 0, 0);
            __builtin_amdgcn_s_setprio(0);
        }

        float pg[32];
#pragma unroll
        for (int j = 0; j < 16; ++j) pg[j] = __builtin_amdgcn_exp2f(st[0][j]);
#pragma unroll
        for (int j = 0; j < 16; ++j) pg[16 + j] = __builtin_amdgcn_exp2f(st[1][j]);

        i32x4 pwv[4];
#pragma unroll
        for (int g = 0; g < 4; ++g) {
            unsigned u0, u1, u2, u3;
            asm("v_cvt_pk_bf16_f32 %0, %1, %2" : "=v"(u0) : "v"(pg[g * 8 + 0]), "v"(pg[g * 8 + 1]));
            asm("v_cvt_pk_bf16_f32 %0, %1, %2" : "=v"(u1) : "v"(pg[g * 8 + 2]), "v"(pg[g * 8 + 3]));
            asm("v_cvt_pk_bf16_f32 %0, %1, %2" : "=v"(u2) : "v"(pg[g * 8 + 4]), "v"(pg[g * 8 + 5]));
            asm("v_cvt_pk_bf16_f32 %0, %1, %2" : "=v"(u3) : "v"(pg[g * 8 + 6]), "v"(pg[g * 8 + 7]));
            asm("v_permlane32_swap_b32 %0, %1" : "+v"(u0), "+v"(u2));
            asm("v_permlane32_swap_b32 %0, %1" : "+v"(u1), "+v"(u3));
            pwv[g][0] = (int)u0; pwv[g][1] = (int)u1; pwv[g][2] = (int)u2; pwv[g][3] = (int)u3;
        }

        float rs;
        {
            float s0 = (pg[0] + pg[1]) + (pg[2] + pg[3]);
            float s1 = (pg[4] + pg[5]) + (pg[6] + pg[7]);
            float s2 = (pg[8] + pg[9]) + (pg[10] + pg[11]);
            float s3 = (pg[12] + pg[13]) + (pg[14] + pg[15]);
            float s4 = (pg[16] + pg[17]) + (pg[18] + pg[19]);
            float s5 = (pg[20] + pg[21]) + (pg[22] + pg[23]);
            float s6 = (pg[24] + pg[25]) + (pg[26] + pg[27]);
            float s7 = (pg[28] + pg[29]) + (pg[30] + pg[31]);
            rs = ((s0 + s1) + (s2 + s3)) + ((s4 + s5) + (s6 + s7));
        }
        rs += __shfl_xor(rs, 32);
        lsum += rs;

        __builtin_amdgcn_s_setprio(1);
#pragma unroll
        for (int dblk = 0; dblk < 2; ++dblk) {
#pragma unroll
            for (int ks = 0; ks < 4; ++ks) {
                int row = dblk * 32 + lq;
                int o = vcur + ((row * 128 + ks * 32 + hi * 16) ^ ((row & 7) << 4));
                bf16x8 vf = *(const bf16x8*)(smem + o);
                oacc[dblk] = __builtin_amdgcn_mfma_f32_32x32x16_bf16(
                    __builtin_bit_cast(bf16x8, pwv[ks]), vf, oacc[dblk], 0, 0, 0);
            }
        }
        __builtin_amdgcn_s_setprio(0);

        __syncthreads();
    }

    {
        float inv = 1.0f / lsum;
#pragma unroll
        for (int r = 0; r < 16; ++r) {
            int crow = (r & 3) + 8 * (r >> 2) + 4 * hi;
            float invr = __shfl(inv, crow);
            int grow = qb0 + w * 32 + crow;
            size_t base = (bS + grow) * QKVLD + headoff + lq;
            og[base]      = f2bf(oacc[0][r] * invr);
            og[base + 32] = f2bf(oacc[1][r] * invr);
        }
    }
}

// ---------------------------------------------------------------------------
extern "C" void kernel_launch(void* const* d_in, const int* in_sizes, int n_in,
                              void* d_out, int out_size, void* d_ws, size_t ws_size,
                              hipStream_t stream) {
    const float* x  = (const float*)d_in[0];
    const float* Wq = (const float*)d_in[1];
    const float* Wk = (const float*)d_in[2];
    const float* Wv = (const float*)d_in[3];
    const float* Wo = (const float*)d_in[4];
    float* out = (float*)d_out;

    const size_t BSD = (size_t)BB * SS * DDIM;     // 8388608
    const size_t WSZ = (size_t)DDIM * DDIM;        // 1048576

    unsigned short* xb   = (unsigned short*)d_ws;          // [8192][1024]
    unsigned short* wqkv = xb + BSD;                       // [3072][1024]
    unsigned short* wob  = wqkv + 3 * WSZ;                 // [1024][1024]
    unsigned short* qkv  = wob + WSZ;                      // [8192][3072]
    unsigned short* vt   = qkv + (size_t)BB * SS * QKVLD;  // [B][H][64][2048]
    float* cosT = (float*)(vt + BSD);
    float* sinT = cosT + (size_t)SS * 32;

    // merged prep: x-cvt (8192) + W-cvt (4096) + rope table (256)
    hipLaunchKernelGGL(prep_all, dim3(12544), dim3(256), 0, stream,
                       x, Wq, Wk, Wv, Wo, xb, wqkv, wob, cosT, sinT);

    // fused QKV projection: 256^2 8-phase + rope/scale + V-transpose epilogues
    hipLaunchKernelGGL(gemm256_qkv, dim3(QKVLD / 256, BB * SS / 256), dim3(512), 0, stream,
                       xb, wqkv, qkv, cosT, sinT, vt);

    // attention: 8 waves/block, 256 q-rows, grid 512 = 2 blocks/CU exactly
    hipLaunchKernelGGL(attn_mfma12, dim3(512), dim3(512), 0, stream, qkv, vt, qkv);

    // output projection: 256x128-tile 8-phase, 256 blocks = 1 full round
    hipLaunchKernelGGL(gemm_out256, dim3(DDIM / 128, BB * SS / 256), dim3(512), 0, stream,
                       qkv, wob, out);
}

// Round 19
// 180.321 us; speedup vs baseline: 1.0207x; 1.0002x over previous
//
#include <hip/hip_runtime.h>
#include <math.h>
#include <stdint.h>

#define BB 4
#define SS 2048
#define DDIM 1024
#define HH 16
#define HD 64
#define QKVLD 3072
#define QSCALE (0.125f * 1.44269504089f)

typedef __bf16 bf16x8 __attribute__((ext_vector_type(8)));
typedef float f32x4 __attribute__((ext_vector_type(4)));
typedef float f32x16 __attribute__((ext_vector_type(16)));
typedef int i32x4 __attribute__((ext_vector_type(4)));

// ---------------- helpers ----------------
__device__ __forceinline__ unsigned short f2bf(float f) {
    union { float f; unsigned u; } v; v.f = f;
    unsigned r = (v.u + 0x7FFFu + ((v.u >> 16) & 1u)) >> 16;
    return (unsigned short)r;
}
__device__ __forceinline__ void gload_lds16(const unsigned short* g, unsigned char* s) {
    __builtin_amdgcn_global_load_lds(
        (const __attribute__((address_space(1))) unsigned int*)(g),
        (__attribute__((address_space(3))) unsigned int*)(s), 16, 0, 0);
}

// ---------------------------------------------------------------------------
// Merged prep: x -> bf16 (8192 blks), W4 -> bf16 (4096 blks), rope table (256)
// ---------------------------------------------------------------------------
__global__ void prep_all(const float* __restrict__ x,
                         const float* __restrict__ Wq, const float* __restrict__ Wk,
                         const float* __restrict__ Wv, const float* __restrict__ Wo,
                         unsigned short* __restrict__ xb,
                         unsigned short* __restrict__ wqkv, unsigned short* __restrict__ wob,
                         float* __restrict__ cosT, float* __restrict__ sinT) {
    int bid = blockIdx.x;
    if (bid < 8192) {
        int i = bid * 256 + threadIdx.x;
        float4 v = ((const float4*)x)[i];
        ushort4 o;
        o.x = f2bf(v.x); o.y = f2bf(v.y); o.z = f2bf(v.z); o.w = f2bf(v.w);
        ((ushort4*)xb)[i] = o;
    } else if (bid < 12288) {
        int i = (bid - 8192) * 256 + threadIdx.x;
        int mat = i >> 18;
        int off = i & 262143;
        const float* src = (mat == 0) ? Wq : (mat == 1) ? Wk : (mat == 2) ? Wv : Wo;
        unsigned short* dst = (mat < 3) ? (wqkv + (size_t)mat * 1048576) : wob;
        float4 v = ((const float4*)src)[off];
        ushort4 o;
        o.x = f2bf(v.x); o.y = f2bf(v.y); o.z = f2bf(v.z); o.w = f2bf(v.w);
        ((ushort4*)dst)[off] = o;
    } else {
        int idx = (bid - 12288) * 256 + threadIdx.x;
        int s = idx >> 5;
        int j = idx & 31;
        float invf = powf(10000.0f, -(float)j / 32.0f);
        float ang = (float)s * invf;
        cosT[idx] = cosf(ang);
        sinT[idx] = sinf(ang);
    }
}

// ---------------------------------------------------------------------------
// 256x256 8-wave 8-phase bf16 GEMM, qkv epilogue (verified rounds 12-13,15-18)
// ---------------------------------------------------------------------------
__global__ __launch_bounds__(512) void gemm256_qkv(const unsigned short* __restrict__ A,
                                                   const unsigned short* __restrict__ Bm,
                                                   unsigned short* __restrict__ C,
                                                   const float* __restrict__ cosT,
                                                   const float* __restrict__ sinT,
                                                   unsigned short* __restrict__ vt) {
    __shared__ unsigned char smem[131072];
    const int t = threadIdx.x;
    const int l = t & 63;
    const int w = t >> 6;
    const int wm = w >> 2;
    const int wn = w & 3;
    const int K = DDIM;
    const int NT = K >> 6;

    const int bid = blockIdx.y * gridDim.x + blockIdx.x;
    const int cpx = (gridDim.x * gridDim.y) >> 3;
    const int swz = (bid & 7) * cpx + (bid >> 3);
    const int row0 = (swz / gridDim.x) * 256;
    const int col0 = (swz % gridDim.x) * 256;

    f32x4 acc[8][4];
#pragma unroll
    for (int i = 0; i < 8; ++i)
#pragma unroll
        for (int j = 0; j < 4; ++j) acc[i][j] = f32x4{0.f, 0.f, 0.f, 0.f};

    const unsigned short* aSg = A + (size_t)(row0 + w * 16 + (l >> 3)) * K + ((l & 7) ^ (l >> 3)) * 8;
    const unsigned short* bSg = Bm + (size_t)(col0 + w * 16 + (l >> 3)) * K + ((l & 7) ^ (l >> 3)) * 8;
    const int dRow = (w * 16) * 128;

#define STAGE_A(kt, h, j, buf) \
    gload_lds16(aSg + (size_t)((h) * 128 + (j) * 8) * K + (kt) * 64, \
                smem + (buf) * 65536 + (h) * 16384 + dRow + (j) * 1024)
#define STAGE_B(kt, h, j, buf) \
    gload_lds16(bSg + (size_t)((h) * 128 + (j) * 8) * K + (kt) * 64, \
                smem + (buf) * 65536 + 32768 + (h) * 16384 + dRow + (j) * 1024)

    STAGE_B(0, 0, 0, 0); STAGE_B(0, 0, 1, 0); STAGE_B(0, 1, 0, 0); STAGE_B(0, 1, 1, 0);
    STAGE_A(0, 0, 0, 0); STAGE_A(0, 0, 1, 0); STAGE_A(0, 1, 0, 0); STAGE_A(0, 1, 1, 0);
    STAGE_B(1, 0, 0, 1); STAGE_B(1, 0, 1, 1); STAGE_B(1, 1, 0, 1); STAGE_B(1, 1, 1, 1);
    asm volatile("s_waitcnt vmcnt(4)" ::: "memory");
    __builtin_amdgcn_s_barrier();

    const int cA = (l >> 4) << 4;
    const int swr = (l & 7) << 4;
    const int rA0 = wm * 128 + (l & 15);
    const int rB0 = wn * 64 + (l & 15);

    int cur = 0;
    for (int u = 0; u < NT; ++u) {
        const int nxt = cur ^ 1;
        const unsigned char* Ab = smem + cur * 65536;
        const unsigned char* Bb = smem + cur * 65536 + 32768;
        const bool pA = (u + 1 < NT);
        const bool pB = (u + 2 < NT);
        bf16x8 bfr[4][2];

#pragma unroll
        for (int p = 0; p < 4; ++p) {
            if (p == 0) { if (pA) { STAGE_A(u + 1, 0, 0, nxt); STAGE_A(u + 1, 0, 1, nxt); } }
            if (p == 1) { if (pA) { STAGE_A(u + 1, 1, 0, nxt); STAGE_A(u + 1, 1, 1, nxt); } }
            if (p == 2) { if (pB) { STAGE_B(u + 2, 0, 0, cur); STAGE_B(u + 2, 0, 1, cur); } }
            if (p == 3) { if (pB) { STAGE_B(u + 2, 1, 0, cur); STAGE_B(u + 2, 1, 1, cur); } }

            if (p == 0) {
#pragma unroll
                for (int ni = 0; ni < 4; ++ni)
#pragma unroll
                    for (int kk = 0; kk < 2; ++kk) {
                        int row = rB0 + ni * 16;
                        bfr[ni][kk] = *(const bf16x8*)(Bb + (row * 128 + ((kk * 64 + cA) ^ swr)));
                    }
            }
            bf16x8 af[2][2];
#pragma unroll
            for (int m2 = 0; m2 < 2; ++m2)
#pragma unroll
                for (int kk = 0; kk < 2; ++kk) {
                    int row = rA0 + (p * 2 + m2) * 16;
                    af[m2][kk] = *(const bf16x8*)(Ab + (row * 128 + ((kk * 64 + cA) ^ swr)));
                }

            __builtin_amdgcn_s_barrier();
            asm volatile("s_waitcnt lgkmcnt(0)" ::: "memory");
            __builtin_amdgcn_sched_barrier(0);
            __builtin_amdgcn_s_setprio(1);
#pragma unroll
            for (int m2 = 0; m2 < 2; ++m2)
#pragma unroll
                for (int ni = 0; ni < 4; ++ni)
#pragma unroll
                    for (int kk = 0; kk < 2; ++kk)
                        acc[p * 2 + m2][ni] = __builtin_amdgcn_mfma_f32_16x16x32_bf16(
                            af[m2][kk], bfr[ni][kk], acc[p * 2 + m2][ni], 0, 0, 0);
            __builtin_amdgcn_s_setprio(0);
            if (p == 3) {
                if (u < NT - 2) asm volatile("s_waitcnt vmcnt(4)" ::: "memory");
                else            asm volatile("s_waitcnt vmcnt(0)" ::: "memory");
            }
            __builtin_amdgcn_s_barrier();
        }
        cur = nxt;
    }
#undef STAGE_A
#undef STAGE_B

    const int cr = (l >> 4) << 2;
    const int cc = l & 15;
    const int sec = (col0 + wn * 64) >> 10;

    if (sec == 2) {
#pragma unroll
        for (int mi = 0; mi < 8; ++mi) {
            int s0 = row0 + wm * 128 + mi * 16 + cr;
            int bI = s0 >> 11;
            int sI = s0 & (SS - 1);
#pragma unroll
            for (int ni = 0; ni < 4; ++ni) {
                int vcol = col0 + wn * 64 + ni * 16 + cc - 2048;
                int hh = vcol >> 6, dd = vcol & 63;
                ushort4 o;
                o.x = f2bf(acc[mi][ni][0]);
                o.y = f2bf(acc[mi][ni][1]);
                o.z = f2bf(acc[mi][ni][2]);
                o.w = f2bf(acc[mi][ni][3]);
                *(ushort4*)&vt[((size_t)((bI * HH + hh) * HD + dd)) * SS + sI] = o;
            }
        }
    } else {
        const float qs = (sec == 0) ? QSCALE : 1.0f;
#pragma unroll
        for (int mi = 0; mi < 8; ++mi) {
#pragma unroll
            for (int r = 0; r < 4; ++r) {
                int grow = row0 + wm * 128 + mi * 16 + cr + r;
                int s = grow & (SS - 1);
#pragma unroll
                for (int ni = 0; ni < 2; ++ni) {
                    int j = ni * 16 + cc;
                    float c = cosT[(s << 5) + j];
                    float sn = sinT[(s << 5) + j];
                    float x1 = acc[mi][ni][r], x2 = acc[mi][ni + 2][r];
                    int gcol = col0 + wn * 64 + j;
                    C[(size_t)grow * QKVLD + gcol]      = f2bf((x1 * c - x2 * sn) * qs);
                    C[(size_t)grow * QKVLD + gcol + 32] = f2bf((x2 * c + x1 * sn) * qs);
                }
            }
        }
    }
}

// ---------------------------------------------------------------------------
// 256x128-tile 8-wave 8-phase bf16 GEMM, f32 C — output projection.
// (verified rounds 13,15,16,18; 256 blocks = 1 full round)
// ---------------------------------------------------------------------------
__global__ __launch_bounds__(512) void gemm_out256(const unsigned short* __restrict__ A,
                                                   const unsigned short* __restrict__ Bm,
                                                   float* __restrict__ C) {
    __shared__ unsigned char smem[98304];
    const int t = threadIdx.x;
    const int l = t & 63;
    const int w = t >> 6;
    const int wm = w >> 2;
    const int wn = w & 3;
    const int K = DDIM;
    const int NT = K >> 6;

    const int bid = blockIdx.y * gridDim.x + blockIdx.x;
    const int cpx = (gridDim.x * gridDim.y) >> 3;
    const int swz = (bid & 7) * cpx + (bid >> 3);
    const int row0 = (swz / gridDim.x) * 256;
    const int col0 = (swz % gridDim.x) * 128;

    f32x4 acc[8][2];
#pragma unroll
    for (int i = 0; i < 8; ++i)
#pragma unroll
        for (int j = 0; j < 2; ++j) acc[i][j] = f32x4{0.f, 0.f, 0.f, 0.f};

    const unsigned short* aSg = A + (size_t)(row0 + w * 8 + (l >> 3)) * QKVLD + ((l & 7) ^ (l >> 3)) * 8;
    const unsigned short* bSg = Bm + (size_t)(col0 + w * 8 + (l >> 3)) * K + ((l & 7) ^ (l >> 3)) * 8;
    const int dRow = (w * 8) * 128;

#define SA(kt, c, buf) \
    gload_lds16(aSg + (size_t)((c) * 64) * QKVLD + (kt) * 64, \
                smem + (buf) * 49152 + (c) * 8192 + dRow)
#define SB(kt, c, buf) \
    gload_lds16(bSg + (size_t)((c) * 64) * K + (kt) * 64, \
                smem + (buf) * 49152 + 32768 + (c) * 8192 + dRow)

    SB(0, 0, 0); SB(0, 1, 0);
    SA(0, 0, 0); SA(0, 1, 0); SA(0, 2, 0); SA(0, 3, 0);
    SB(1, 0, 1); SB(1, 1, 1);
    asm volatile("s_waitcnt vmcnt(2)" ::: "memory");
    __builtin_amdgcn_s_barrier();

    const int cA = (l >> 4) << 4;
    const int swr = (l & 7) << 4;
    const int rA0 = wm * 128 + (l & 15);
    const int rB0 = wn * 32 + (l & 15);

    int cur = 0;
    for (int u = 0; u < NT; ++u) {
        const int nxt = cur ^ 1;
        const unsigned char* Ab = smem + cur * 49152;
        const unsigned char* Bb = smem + cur * 49152 + 32768;
        const bool pA = (u + 1 < NT);
        const bool pB = (u + 2 < NT);
        bf16x8 bfr[2][2];

#pragma unroll
        for (int p = 0; p < 4; ++p) {
            if (p == 0) { if (pA) { SA(u + 1, 0, nxt); SA(u + 1, 1, nxt); } }
            if (p == 1) { if (pA) { SA(u + 1, 2, nxt); SA(u + 1, 3, nxt); } }
            if (p == 2) { if (pB) { SB(u + 2, 0, cur); } }
            if (p == 3) { if (pB) { SB(u + 2, 1, cur); } }

            if (p == 0) {
#pragma unroll
                for (int ni = 0; ni < 2; ++ni)
#pragma unroll
                    for (int kk = 0; kk < 2; ++kk) {
                        int row = rB0 + ni * 16;
                        bfr[ni][kk] = *(const bf16x8*)(Bb + (row * 128 + ((kk * 64 + cA) ^ swr)));
                    }
            }
            bf16x8 af[2][2];
#pragma unroll
            for (int m2 = 0; m2 < 2; ++m2)
#pragma unroll
                for (int kk = 0; kk < 2; ++kk) {
                    int row = rA0 + (p * 2 + m2) * 16;
                    af[m2][kk] = *(const bf16x8*)(Ab + (row * 128 + ((kk * 64 + cA) ^ swr)));
                }

            __builtin_amdgcn_s_barrier();
            asm volatile("s_waitcnt lgkmcnt(0)" ::: "memory");
            __builtin_amdgcn_sched_barrier(0);
            __builtin_amdgcn_s_setprio(1);
#pragma unroll
            for (int m2 = 0; m2 < 2; ++m2)
#pragma unroll
                for (int ni = 0; ni < 2; ++ni)
#pragma unroll
                    for (int kk = 0; kk < 2; ++kk)
                        acc[p * 2 + m2][ni] = __builtin_amdgcn_mfma_f32_16x16x32_bf16(
                            af[m2][kk], bfr[ni][kk], acc[p * 2 + m2][ni], 0, 0, 0);
            __builtin_amdgcn_s_setprio(0);
            if (p == 3) {
                if (u < NT - 2) asm volatile("s_waitcnt vmcnt(2)" ::: "memory");
                else            asm volatile("s_waitcnt vmcnt(0)" ::: "memory");
            }
            __builtin_amdgcn_s_barrier();
        }
        cur = nxt;
    }
#undef SA
#undef SB

    const int cr = (l >> 4) << 2;
    const int cc = l & 15;
#pragma unroll
    for (int mi = 0; mi < 8; ++mi)
#pragma unroll
        for (int ni = 0; ni < 2; ++ni) {
            int gcol = col0 + wn * 32 + ni * 16 + cc;
#pragma unroll
            for (int r = 0; r < 4; ++r) {
                int grow = row0 + wm * 128 + mi * 16 + cr + r;
                C[(size_t)grow * DDIM + gcol] = acc[mi][ni][r];
            }
        }
}

// ---------------------------------------------------------------------------
// MFMA flash attention v13: v12 + 3-deep K/V buffering with counted vmcnt.
// Raw s_barrier + vmcnt(2) keeps the newest tile's 2 loads in flight across
// the barrier (removes the __syncthreads vmcnt(0) drain). Hazards:
//  - tile t ready at iter-t top: end-of-(t-1) waits vmcnt(2) -> only (t+1)'s
//    loads outstanding, and (t+2 < NT ? 2 : 0) = vmcnt(0) at the NT-2 edge.
//  - WAR on buf (t+2)%3 == (t-1)%3: all waves passed the end-of-(t-1)
//    barrier (done reading) before iter-t issues.
// LDS 48KB -> still 2 blocks/CU. All math identical to verified v12.
// ---------------------------------------------------------------------------
__global__ __launch_bounds__(512) void attn_mfma13(const unsigned short* __restrict__ qkv,
                                                   const unsigned short* __restrict__ vt,
                                                   unsigned short* __restrict__ og) {
    __shared__ unsigned char smem[49152];
    const int tid = threadIdx.x;
    const int ln = tid & 63;
    const int w = tid >> 6;        // 0..7
    const int lq = ln & 31;
    const int hi = ln >> 5;
    const int NTK = SS / 64;       // 32

    const int did = blockIdx.x;
    const int b = did & 3;
    const int h = (did >> 2) & 15;
    const int qb0 = (did >> 6) << 8;   // 256 q-rows per block

    const int headoff = h * HD;
    const size_t bS = (size_t)b * SS;

    bf16x8 qf[4];
    {
        const unsigned short* qsrc = qkv + (bS + qb0 + w * 32 + lq) * QKVLD + headoff + hi * 8;
#pragma unroll
        for (int dc = 0; dc < 4; ++dc)
            qf[dc] = *(const bf16x8*)(qsrc + dc * 16);
    }

    f32x16 oacc[2];
#pragma unroll
    for (int i = 0; i < 2; ++i)
#pragma unroll
        for (int r = 0; r < 16; ++r) oacc[i][r] = 0.f;
    float lsum = 0.f;

    f32x16 fzero;
#pragma unroll
    for (int r = 0; r < 16; ++r) fzero[r] = 0.f;

    const int srow = w * 8 + (ln >> 3);
    const int scol = ((ln & 7) ^ (ln >> 3)) << 3;
    const unsigned short* kbase_g = qkv + bS * QKVLD + 1024 + headoff;
    const unsigned short* vtbase_g = vt + (size_t)(b * HH + h) * HD * SS;

    // prologue: stage tiles 0 and 1 (issue order K0,V0,K1,V1 per wave)
    {
        gload_lds16(kbase_g + (size_t)srow * QKVLD + scol,        smem + w * 1024);
        gload_lds16(vtbase_g + (size_t)srow * SS + scol,          smem + 24576 + w * 1024);
        gload_lds16(kbase_g + (size_t)(64 + srow) * QKVLD + scol, smem + 8192 + w * 1024);
        gload_lds16(vtbase_g + (size_t)srow * SS + 64 + scol,     smem + 24576 + 8192 + w * 1024);
    }
    asm volatile("s_waitcnt vmcnt(2)" ::: "memory");   // tile 0 landed
    __builtin_amdgcn_s_barrier();
    asm volatile("" ::: "memory");

#pragma unroll 3
    for (int tkv = 0; tkv < NTK; ++tkv) {
        const int cb = tkv % 3;
        const int sb = (tkv + 2) % 3;
        const int kcur = cb * 8192;
        const int vcur = 24576 + cb * 8192;
        if (tkv + 2 < NTK) {
            const int kv2 = (tkv + 2) * 64;
            gload_lds16(kbase_g + (size_t)(kv2 + srow) * QKVLD + scol,
                        smem + sb * 8192 + w * 1024);
            gload_lds16(vtbase_g + (size_t)srow * SS + kv2 + scol,
                        smem + 24576 + sb * 8192 + w * 1024);
        }

        f32x16 st[2];
#pragma unroll
        for (int kb = 0; kb < 2; ++kb) {
            bf16x8 kf[4];
#pragma unroll
            for (int dc = 0; dc < 4; ++dc) {
                int row = kb * 32 + lq;
                int o = kcur + ((row * 128 + dc * 32 + hi * 16) ^ ((row & 7) << 4));
                kf[dc] = *(const bf16x8*)(smem + o);
            }
            __builtin_amdgcn_s_setprio(1);
            st[kb] = __builtin_amdgcn_mfma_f32_32x32x16_bf16(kf[0], qf[0], fzero, 0, 0, 0);
#pragma unroll
            for (int dc = 1; dc < 4; ++dc)
                st[kb] = __builtin_amdgcn_mfma_f32_32x32x16_bf16(kf[dc], qf[dc], st[kb], 0, 0, 0);
            __builtin_amdgcn_s_setprio(0);
        }

        float pg[32];
#pragma unroll
        for (int j = 0; j < 16; ++j) pg[j] = __builtin_amdgcn_exp2f(st[0][j]);
#pragma unroll
        for (int j = 0; j < 16; ++j) pg[16 + j] = __builtin_amdgcn_exp2f(st[1][j]);

        i32x4 pwv[4];
#pragma unroll
        for (int g = 0; g < 4; ++g) {
            unsigned u0, u1, u2, u3;
            asm("v_cvt_pk_bf16_f32 %0, %1, %2" : "=v"(u0) : "v"(pg[g * 8 + 0]), "v"(pg[g * 8 + 1]));
            asm("v_cvt_pk_bf16_f32 %0, %1, %2" : "=v"(u1) : "v"(pg[g * 8 + 2]), "v"(pg[g * 8 + 3]));
            asm("v_cvt_pk_bf16_f32 %0, %1, %2" : "=v"(u2) : "v"(pg[g * 8 + 4]), "v"(pg[g * 8 + 5]));
            asm("v_cvt_pk_bf16_f32 %0, %1, %2" : "=v"(u3) : "v"(pg[g * 8 + 6]), "v"(pg[g * 8 + 7]));
            asm("v_permlane32_swap_b32 %0, %1" : "+v"(u0), "+v"(u2));
            asm("v_permlane32_swap_b32 %0, %1" : "+v"(u1), "+v"(u3));
            pwv[g][0] = (int)u0; pwv[g][1] = (int)u1; pwv[g][2] = (int)u2; pwv[g][3] = (int)u3;
        }

        float rs;
        {
            float s0 = (pg[0] + pg[1]) + (pg[2] + pg[3]);
            float s1 = (pg[4] + pg[5]) + (pg[6] + pg[7]);
            float s2 = (pg[8] + pg[9]) + (pg[10] + pg[11]);
            float s3 = (pg[12] + pg[13]) + (pg[14] + pg[15]);
            float s4 = (pg[16] + pg[17]) + (pg[18] + pg[19]);
            float s5 = (pg[20] + pg[21]) + (pg[22] + pg[23]);
            float s6 = (pg[24] + pg[25]) + (pg[26] + pg[27]);
            float s7 = (pg[28] + pg[29]) + (pg[30] + pg[31]);
            rs = ((s0 + s1) + (s2 + s3)) + ((s4 + s5) + (s6 + s7));
        }
        rs += __shfl_xor(rs, 32);
        lsum += rs;

        __builtin_amdgcn_s_setprio(1);
#pragma unroll
        for (int dblk = 0; dblk < 2; ++dblk) {
#pragma unroll
            for (int ks = 0; ks < 4; ++ks) {
                int row = dblk * 32 + lq;
                int o = vcur + ((row * 128 + ks * 32 + hi * 16) ^ ((row & 7) << 4));
                bf16x8 vf = *(const bf16x8*)(smem + o);
                oacc[dblk] = __builtin_amdgcn_mfma_f32_32x32x16_bf16(
                    __builtin_bit_cast(bf16x8, pwv[ks]), vf, oacc[dblk], 0, 0, 0);
            }
        }
        __builtin_amdgcn_s_setprio(0);

        // counted-vmcnt barrier: tile t+1 must be ready; allow (t+2)'s loads
        // (issued this iter) to stay in flight.
        if (tkv + 2 < NTK) asm volatile("s_waitcnt vmcnt(2)" ::: "memory");
        else               asm volatile("s_waitcnt vmcnt(0)" ::: "memory");
        __builtin_amdgcn_s_barrier();
        asm volatile("" ::: "memory");
    }

    {
        float inv = 1.0f / lsum;
#pragma unroll
        for (int r = 0; r < 16; ++r) {
            int crow = (r & 3) + 8 * (r >> 2) + 4 * hi;
            float invr = __shfl(inv, crow);
            int grow = qb0 + w * 32 + crow;
            size_t base = (bS + grow) * QKVLD + headoff + lq;
            og[base]      = f2bf(oacc[0][r] * invr);
            og[base + 32] = f2bf(oacc[1][r] * invr);
        }
    }
}

// ---------------------------------------------------------------------------
extern "C" void kernel_launch(void* const* d_in, const int* in_sizes, int n_in,
                              void* d_out, int out_size, void* d_ws, size_t ws_size,
                              hipStream_t stream) {
    const float* x  = (const float*)d_in[0];
    const float* Wq = (const float*)d_in[1];
    const float* Wk = (const float*)d_in[2];
    const float* Wv = (const float*)d_in[3];
    const float* Wo = (const float*)d_in[4];
    float* out = (float*)d_out;

    const size_t BSD = (size_t)BB * SS * DDIM;     // 8388608
    const size_t WSZ = (size_t)DDIM * DDIM;        // 1048576

    unsigned short* xb   = (unsigned short*)d_ws;          // [8192][1024]
    unsigned short* wqkv = xb + BSD;                       // [3072][1024]
    unsigned short* wob  = wqkv + 3 * WSZ;                 // [1024][1024]
    unsigned short* qkv  = wob + WSZ;                      // [8192][3072]
    unsigned short* vt   = qkv + (size_t)BB * SS * QKVLD;  // [B][H][64][2048]
    float* cosT = (float*)(vt + BSD);
    float* sinT = cosT + (size_t)SS * 32;

    // merged prep: x-cvt (8192) + W-cvt (4096) + rope table (256)
    hipLaunchKernelGGL(prep_all, dim3(12544), dim3(256), 0, stream,
                       x, Wq, Wk, Wv, Wo, xb, wqkv, wob, cosT, sinT);

    // fused QKV projection: 256^2 8-phase + rope/scale + V-transpose epilogues
    hipLaunchKernelGGL(gemm256_qkv, dim3(QKVLD / 256, BB * SS / 256), dim3(512), 0, stream,
                       xb, wqkv, qkv, cosT, sinT, vt);

    // attention: 8 waves/block, 256 q-rows, 3-deep K/V pipeline, counted vmcnt
    hipLaunchKernelGGL(attn_mfma13, dim3(512), dim3(512), 0, stream, qkv, vt, qkv);

    // output projection: 256x128-tile 8-phase, 256 blocks = 1 full round
    hipLaunchKernelGGL(gemm_out256, dim3(DDIM / 128, BB * SS / 256), dim3(512), 0, stream,
                       qkv, wob, out);
}